// Round 13
// baseline (332.452 us; speedup 1.0000x reference)
//
#include <hip/hip_runtime.h>
#include <hip/hip_bf16.h>
#include <math.h>

#define NN 50000
#define EE 800000
#define NB ((NN + 255) / 256)   // 196 scan blocks

typedef __attribute__((ext_vector_type(8))) short bf16x8;
typedef __attribute__((ext_vector_type(4))) float f32x4;
typedef __attribute__((ext_vector_type(8))) float f32x8;

__device__ __forceinline__ short f2bf(float f) {
  __hip_bfloat16 h = __float2bfloat16(f);   // RTNE
  return __builtin_bit_cast(short, h);
}
__device__ __forceinline__ float bf2f(short h) {
  return __uint_as_float(((unsigned)(unsigned short)h) << 16);
}

typedef const __attribute__((address_space(1))) unsigned int* gas_ptr;
typedef __attribute__((address_space(3))) unsigned int* las_ptr;
__device__ __forceinline__ void gload16(const void* g, void* l) {
  __builtin_amdgcn_global_load_lds((gas_ptr)g, (las_ptr)l, 16, 0, 0);
}

// ---------------------------------------------------------------------------
// Wt builder: w [K][128] f32 -> wt [128][2K] bf16 rows = [hi | lo]
// ---------------------------------------------------------------------------
__global__ void build_wt(const float* __restrict__ w, short* __restrict__ wt, int K)
{
  int idx = blockIdx.x * 256 + threadIdx.x;
  if (idx >= 128 * K) return;
  int k = idx % K;
  int c = idx / K;
  float v = w[(size_t)k * 128 + c];
  short hi = f2bf(v);
  short lo = f2bf(v - bf2f(hi));
  size_t base = (size_t)c * 2 * K;
  wt[base + k] = hi;
  wt[base + K + k] = lo;
}

// ---------------------------------------------------------------------------
// Split-precision MFMA GEMM (round-12, known-good): async global_load_lds
// staging (A f32 in LDS, hi/lo conversion in MFMA phase), linear LDS dest +
// inverse-swizzled global source. bn=0 = 3-product; bn=1 = 1-product bf16.
// ---------------------------------------------------------------------------
template <int K, int KS>   // KS = K/64
__global__ __launch_bounds__(256) void gemm_mfma(
    const float* __restrict__ A, int M,
    const short* __restrict__ Wt0, const float* __restrict__ b0,
    const short* __restrict__ Wt1, const float* __restrict__ b1,
    float* __restrict__ out)
{
  const int bn = blockIdx.y;
  const bool full = (bn == 0);
  const short* __restrict__ Wt = bn ? Wt1 : Wt0;
  const float* __restrict__ bias = bn ? b1 : b0;
  __shared__ __align__(16) float As_f32[128][64];   // 32 KB
  __shared__ __align__(16) short Ws_hi[128][64];    // 16 KB
  __shared__ __align__(16) short Ws_lo[128][64];    // 16 KB
  const int tid = threadIdx.x;
  const int m0 = blockIdx.x * 128;
  const int lane = tid & 63;
  const int wv = tid >> 6;
  const int wr = wv >> 1, wc = wv & 1;
  const int rsel = lane & 15, ksel = lane >> 4, sx = lane & 7;

  f32x4 acc[4][4];
#pragma unroll
  for (int i = 0; i < 4; ++i)
#pragma unroll
    for (int j = 0; j < 4; ++j) acc[i][j] = (f32x4)(0.f);

  for (int t = 0; t < KS; ++t) {
    const int k0 = t * 64;
#pragma unroll
    for (int i = 0; i < 8; ++i) {
      int L = i * 256 + tid;
      int m = L >> 4, s = L & 15;
      int row = m0 + m;
      row = row < M ? row : M - 1;
      const float* g = A + (size_t)row * K + k0 + ((s ^ ((m & 7) << 1)) << 2);
      gload16(g, (char*)As_f32 + (size_t)L * 16);
    }
#pragma unroll
    for (int i = 0; i < 4; ++i) {
      int L = i * 256 + tid;
      int c = L >> 3, sl = L & 7;
      const short* g = Wt + (size_t)c * (2 * K) + k0 + ((sl ^ (c & 7)) << 3);
      gload16(g, (char*)Ws_hi + (size_t)L * 16);
    }
    if (full) {
#pragma unroll
      for (int i = 0; i < 4; ++i) {
        int L = i * 256 + tid;
        int c = L >> 3, sl = L & 7;
        const short* g = Wt + (size_t)c * (2 * K) + K + k0 + ((sl ^ (c & 7)) << 3);
        gload16(g, (char*)Ws_lo + (size_t)L * 16);
      }
    }
    __syncthreads();
#pragma unroll
    for (int kk = 0; kk < 2; ++kk) {
      bf16x8 ah[4], al[4], bh[4], bl[4];
#pragma unroll
      for (int mf = 0; mf < 4; ++mf) {
        int r = wr * 64 + mf * 16 + rsel;
        int phys = (kk * 8 + ksel * 2) ^ (sx << 1);
        f32x4 a0 = *reinterpret_cast<const f32x4*>(&As_f32[r][phys * 4]);
        f32x4 a1 = *reinterpret_cast<const f32x4*>(&As_f32[r][phys * 4 + 4]);
        float xs[8] = {a0.x, a0.y, a0.z, a0.w, a1.x, a1.y, a1.z, a1.w};
        bf16x8 hi, lo;
#pragma unroll
        for (int j = 0; j < 8; ++j) {
          short h = f2bf(xs[j]);
          hi[j] = h;
          lo[j] = f2bf(xs[j] - bf2f(h));
        }
        ah[mf] = hi;
        al[mf] = lo;
      }
#pragma unroll
      for (int cf = 0; cf < 4; ++cf) {
        int r = wc * 64 + cf * 16 + rsel;
        int sl = ((kk * 4 + ksel) ^ sx) * 8;
        bh[cf] = *reinterpret_cast<const bf16x8*>(&Ws_hi[r][sl]);
        if (full) bl[cf] = *reinterpret_cast<const bf16x8*>(&Ws_lo[r][sl]);
      }
#pragma unroll
      for (int mf = 0; mf < 4; ++mf)
#pragma unroll
        for (int cf = 0; cf < 4; ++cf)
          acc[mf][cf] = __builtin_amdgcn_mfma_f32_16x16x32_bf16(
              ah[mf], bh[cf], acc[mf][cf], 0, 0, 0);
      if (full) {
#pragma unroll
        for (int mf = 0; mf < 4; ++mf)
#pragma unroll
          for (int cf = 0; cf < 4; ++cf) {
            acc[mf][cf] = __builtin_amdgcn_mfma_f32_16x16x32_bf16(
                al[mf], bh[cf], acc[mf][cf], 0, 0, 0);
            acc[mf][cf] = __builtin_amdgcn_mfma_f32_16x16x32_bf16(
                ah[mf], bl[cf], acc[mf][cf], 0, 0, 0);
          }
      }
    }
    __syncthreads();
  }
#pragma unroll
  for (int mf = 0; mf < 4; ++mf) {
#pragma unroll
    for (int j = 0; j < 4; ++j) {
      int row = m0 + wr * 64 + mf * 16 + ksel * 4 + j;
      if (row >= M) continue;
#pragma unroll
      for (int cf = 0; cf < 4; ++cf) {
        int col = wc * 64 + cf * 16 + rsel;
        out[(size_t)row * 256 + bn * 128 + col] = acc[mf][cf][j] + bias[col];
      }
    }
  }
}

// ---------------------------------------------------------------------------
// CSR build: ONE atomic pass (count + position), scan, atomic-free scatter.
// ---------------------------------------------------------------------------
__global__ void count_pos(const int* __restrict__ ei, int* __restrict__ deg,
                          int* __restrict__ pos)
{
  int e = blockIdx.x * 256 + threadIdx.x;
  if (e >= EE) return;
  pos[e] = atomicAdd(&deg[ei[EE + e]], 1);
}

__global__ __launch_bounds__(256) void scan_blocks(const int* __restrict__ deg,
                                                   int* __restrict__ row_off,
                                                   int* __restrict__ bsum)
{
  int b = blockIdx.x, tid = threadIdx.x;
  int i = b * 256 + tid;
  int v = (i < NN) ? deg[i] : 0;
  int lane = tid & 63, wv = tid >> 6;
  int x = v;
#pragma unroll
  for (int off = 1; off < 64; off <<= 1) {
    int t = __shfl_up(x, off);
    if (lane >= off) x += t;
  }
  __shared__ int ws[4], wo[4];
  if (lane == 63) ws[wv] = x;
  __syncthreads();
  if (tid == 0) {
    int s = 0;
#pragma unroll
    for (int k = 0; k < 4; ++k) { wo[k] = s; s += ws[k]; }
    bsum[b] = s;
  }
  __syncthreads();
  x += wo[wv];
  if (i < NN) row_off[i + 1] = x;
}

__global__ __launch_bounds__(256) void scan_tops(const int* __restrict__ bsum,
                                                 int* __restrict__ boff)
{
  int tid = threadIdx.x;
  int v = (tid < NB) ? bsum[tid] : 0;
  int lane = tid & 63, wv = tid >> 6;
  int x = v;
#pragma unroll
  for (int off = 1; off < 64; off <<= 1) {
    int t = __shfl_up(x, off);
    if (lane >= off) x += t;
  }
  __shared__ int ws[4], wo[4];
  if (lane == 63) ws[wv] = x;
  __syncthreads();
  if (tid == 0) {
    int s = 0;
#pragma unroll
    for (int k = 0; k < 4; ++k) { wo[k] = s; s += ws[k]; }
  }
  __syncthreads();
  x += wo[wv];
  if (tid < NB) boff[tid] = x - v;   // exclusive
}

__global__ void scan_add(int* __restrict__ row_off, const int* __restrict__ boff)
{
  int i = blockIdx.x * 256 + threadIdx.x;
  if (i == 0) row_off[0] = 0;
  if (i < NN) row_off[i + 1] += boff[blockIdx.x];
}

__global__ void scatter_edges(const int* __restrict__ ei, const float* __restrict__ ea,
                              const int* __restrict__ row_off,
                              const int* __restrict__ pos, float4* __restrict__ csr)
{
  int e = blockIdx.x * 256 + threadIdx.x;
  if (e >= EE) return;
  int s = ei[e];
  int d = ei[EE + e];
  float e0 = ea[(size_t)e * 3 + 0];
  float e1 = ea[(size_t)e * 3 + 1];
  float e2 = ea[(size_t)e * 3 + 2];
  csr[row_off[d] + pos[e]] = make_float4(__int_as_float(s), e0, e1, e2);
}

// ---------------------------------------------------------------------------
// GATv2 gather v5: wave per dst node, FOUR 16-lane edge-groups per wave.
// Lane owns f32x8 channel octet (16 lanes x 8 = 128 ch). Score reduce =
// 3 shfl levels within 8-lane head halves. Edges strided per group (base+g,
// step 4) so the 4 groups' csr reads per iteration are 64B contiguous.
// 2-edge unroll + 1-pair pipeline + defer-max fast path. 2-round merge
// (xor16, xor32), self-loop (mean attr) at the end.
// ---------------------------------------------------------------------------
__device__ __forceinline__ float score8(f32x8 xl, f32x8 xr, float e0, float e1,
                                        float e2, f32x8 w0, f32x8 w1, f32x8 w2,
                                        f32x8 at)
{
  f32x8 z = xl + xr;
  z = __builtin_elementwise_fma((f32x8)(e0), w0, z);
  z = __builtin_elementwise_fma((f32x8)(e1), w1, z);
  z = __builtin_elementwise_fma((f32x8)(e2), w2, z);
  f32x8 t = __builtin_elementwise_max(z, 0.2f * z);
  f32x8 p = t * at;
  return ((p[0] + p[4]) + (p[1] + p[5])) + ((p[2] + p[6]) + (p[3] + p[7]));
}

template <bool FINAL>
__global__ __launch_bounds__(256) void gat_gather(
    const float* __restrict__ xlr, const int* __restrict__ row_off,
    const float4* __restrict__ csr,
    const float* __restrict__ we, const float* __restrict__ att,
    const float* __restrict__ bo, const float* __restrict__ pw,
    float* __restrict__ out)
{
  __shared__ __align__(32) float we_s[384];
  __shared__ __align__(32) float att_s[128];
  __shared__ __align__(32) float bo_s[64], pw_s[64];
  int tid = threadIdx.x;
  for (int i = tid; i < 384; i += 256) we_s[i] = we[i];
  if (tid < 128) att_s[tid] = att[tid];
  if (tid < 64) { bo_s[tid] = bo[tid]; pw_s[tid] = FINAL ? pw[tid] : 0.f; }
  __syncthreads();

  int wv = tid >> 6, lane = tid & 63;
  int n = blockIdx.x * 4 + wv;   // NN % 4 == 0

  const int g   = lane >> 4;            // edge group 0..3
  const int sub = lane & 15;
  const int cb  = (sub >> 3) * 64 + (sub & 7) * 8;   // channel octet base

  f32x8 xr = *reinterpret_cast<const f32x8*>(&xlr[(size_t)n * 256 + 128 + cb]);
  f32x8 w0 = *reinterpret_cast<const f32x8*>(&we_s[cb]);
  f32x8 w1 = *reinterpret_cast<const f32x8*>(&we_s[128 + cb]);
  f32x8 w2 = *reinterpret_cast<const f32x8*>(&we_s[256 + cb]);
  f32x8 at = *reinterpret_cast<const f32x8*>(&att_s[cb]);

  int ro = row_off[n], re = row_off[n + 1];
  int len = re - ro;
  int base = ro + g;
  int d = re - base;
  int cnt = d > 0 ? (d + 3) >> 2 : 0;   // edges in this group (stride 4)
  int pairs = cnt >> 1, rem = cnt & 1;

  float m = -INFINITY, s = 0.f;
  f32x8 a = (f32x8)(0.f);
  float se0 = 0.f, se1 = 0.f, se2 = 0.f;

  auto PAIR = [&](float4 cA, float4 cB, f32x8 xlA, f32x8 xlB) {
    float vA = score8(xlA, xr, cA.y, cA.z, cA.w, w0, w1, w2, at);
    float vB = score8(xlB, xr, cB.y, cB.z, cB.w, w0, w1, w2, at);
#pragma unroll
    for (int off = 4; off; off >>= 1) {
      vA += __shfl_xor(vA, off);
      vB += __shfl_xor(vB, off);
    }
    float nm = fmaxf(m, fmaxf(vA, vB));
    if (__all(nm == m)) {               // defer-max fast path (uniform branch)
      float qA = __expf(vA - m);
      float qB = __expf(vB - m);
      s += qA + qB;
      a = a + (f32x8)(qA) * xlA + (f32x8)(qB) * xlB;
    } else {
      float sc = __expf(m - nm);
      float qA = __expf(vA - nm);
      float qB = __expf(vB - nm);
      s = s * sc + qA + qB;
      a = a * (f32x8)(sc) + (f32x8)(qA) * xlA + (f32x8)(qB) * xlB;
      m = nm;
    }
    se0 += cA.y + cB.y; se1 += cA.z + cB.z; se2 += cA.w + cB.w;
  };
  auto SINGLE = [&](float4 cA) {
    f32x8 xlA = *reinterpret_cast<const f32x8*>(
        &xlr[(size_t)__float_as_int(cA.x) * 256 + cb]);
    float vA = score8(xlA, xr, cA.y, cA.z, cA.w, w0, w1, w2, at);
#pragma unroll
    for (int off = 4; off; off >>= 1) vA += __shfl_xor(vA, off);
    float nm = fmaxf(m, vA);
    float sc = __expf(m - nm);
    float qA = __expf(vA - nm);
    s = s * sc + qA;
    a = a * (f32x8)(sc) + (f32x8)(qA) * xlA;
    m = nm;
    se0 += cA.y; se1 += cA.z; se2 += cA.w;
  };

  if (pairs > 0) {
    float4 cA = csr[base], cB = csr[base + 4];
    f32x8 xlA = *reinterpret_cast<const f32x8*>(
        &xlr[(size_t)__float_as_int(cA.x) * 256 + cb]);
    f32x8 xlB = *reinterpret_cast<const f32x8*>(
        &xlr[(size_t)__float_as_int(cB.x) * 256 + cb]);
    for (int p = 1; p < pairs; ++p) {
      int j0 = base + 8 * p;
      float4 nA = csr[j0], nB = csr[j0 + 4];
      f32x8 nxA = *reinterpret_cast<const f32x8*>(
          &xlr[(size_t)__float_as_int(nA.x) * 256 + cb]);
      f32x8 nxB = *reinterpret_cast<const f32x8*>(
          &xlr[(size_t)__float_as_int(nB.x) * 256 + cb]);
      PAIR(cA, cB, xlA, xlB);
      cA = nA; cB = nB; xlA = nxA; xlB = nxB;
    }
    PAIR(cA, cB, xlA, xlB);
  }
  if (rem) SINGLE(csr[base + 8 * pairs]);

  // ---- merge the four edge-groups: xor16 then xor32 ----
#pragma unroll
  for (int off = 16; off <= 32; off <<= 1) {
    float m2 = __shfl_xor(m, off);
    float s2 = __shfl_xor(s, off);
    f32x8 a2;
#pragma unroll
    for (int j = 0; j < 8; ++j) a2[j] = __shfl_xor(a[j], off);
    float nm = fmaxf(m, m2);
    nm = (nm == -INFINITY) ? 0.f : nm;   // both-empty guard
    float c1 = __expf(m - nm);
    float c2 = __expf(m2 - nm);
    s = s * c1 + s2 * c2;
    a = a * (f32x8)(c1) + a2 * (f32x8)(c2);
    m = nm;
    se0 += __shfl_xor(se0, off);
    se1 += __shfl_xor(se1, off);
    se2 += __shfl_xor(se2, off);
  }

  // ---- self-loop: src = n, attr = mean of in-edge attrs ----
  {
    float inv = 1.f / fmaxf((float)len, 1.f);
    float me0 = se0 * inv, me1 = se1 * inv, me2 = se2 * inv;
    f32x8 xlS = *reinterpret_cast<const f32x8*>(&xlr[(size_t)n * 256 + cb]);
    float vS = score8(xlS, xr, me0, me1, me2, w0, w1, w2, at);
#pragma unroll
    for (int off = 4; off; off >>= 1) vS += __shfl_xor(vS, off);
    float nm = fmaxf(m, vS);
    float sc = __expf(m - nm);
    float qS = __expf(vS - nm);
    s = s * sc + qS;
    a = a * (f32x8)(sc) + (f32x8)(qS) * xlS;
  }

  // ---- head mean + bias (+PReLU); lanes 0-7 (group 0, head 0) write ----
  f32x8 f = a * (f32x8)(1.f / s);
  f32x8 gx;
#pragma unroll
  for (int j = 0; j < 8; ++j) gx[j] = __shfl_xor(f[j], 8);
  if (lane < 8) {
    int col = sub * 8;                    // sub == lane here, ch [col, col+8)
    f32x8 b8 = *reinterpret_cast<const f32x8*>(&bo_s[col]);
    f32x8 r = 0.5f * (f + gx) + b8;
    if (FINAL) {
      f32x8 p8 = *reinterpret_cast<const f32x8*>(&pw_s[col]);
#pragma unroll
      for (int j = 0; j < 8; ++j) r[j] = (r[j] >= 0.f) ? r[j] : p8[j] * r[j];
    }
    *reinterpret_cast<f32x8*>(&out[(size_t)n * 64 + col]) = r;
  }
}

// ---------------------------------------------------------------------------
extern "C" void kernel_launch(void* const* d_in, const int* in_sizes, int n_in,
                              void* d_out, int out_size, void* d_ws, size_t ws_size,
                              hipStream_t stream)
{
  const float* x     = (const float*)d_in[0];
  const int*   ei    = (const int*)d_in[1];
  const float* eattr = (const float*)d_in[2];
  const float* wl1 = (const float*)d_in[3];
  const float* bl1 = (const float*)d_in[4];
  const float* wr1 = (const float*)d_in[5];
  const float* br1 = (const float*)d_in[6];
  const float* we1 = (const float*)d_in[7];
  const float* att1 = (const float*)d_in[8];
  const float* bo1 = (const float*)d_in[9];
  const float* wl2 = (const float*)d_in[10];
  const float* bl2 = (const float*)d_in[11];
  const float* wr2 = (const float*)d_in[12];
  const float* br2 = (const float*)d_in[13];
  const float* we2 = (const float*)d_in[14];
  const float* att2 = (const float*)d_in[15];
  const float* bo2 = (const float*)d_in[16];
  const float* prelu = (const float*)d_in[17];
  float* out = (float*)d_out;

  float* fws  = (float*)d_ws;
  float* xlr  = fws;                             // N*256 f32
  float* h1   = xlr + (size_t)NN * 256;          // N*64 f32
  float4* csr = (float4*)(h1 + (size_t)NN * 64); // EE float4
  int* deg     = (int*)(csr + EE);               // N
  int* row_off = deg + NN;                       // N+1
  int* bsum    = row_off + NN + 1;               // NB
  int* boff    = bsum + NB;                      // NB
  int* pos     = boff + NB;                      // EE

  // wt1 aliases h1 (dead until gat1 writes h1); wt2 aliases deg (dead after
  // scan; build_wt2 launches after scatter_edges).
  short* wt1a = (short*)h1;
  short* wt1b = wt1a + (size_t)128 * 1024;
  short* wt2a = (short*)deg;
  short* wt2b = wt2a + (size_t)128 * 128;

  hipMemsetAsync(deg, 0, (size_t)NN * 4, stream);

  int ebl = (EE + 255) / 256;

  count_pos<<<ebl, 256, 0, stream>>>(ei, deg, pos);
  scan_blocks<<<NB, 256, 0, stream>>>(deg, row_off, bsum);
  scan_tops<<<1, 256, 0, stream>>>(bsum, boff);
  scan_add<<<NB, 256, 0, stream>>>(row_off, boff);
  scatter_edges<<<ebl, 256, 0, stream>>>(ei, eattr, row_off, pos, csr);

  dim3 ggrid((NN + 127) / 128, 2);

  // layer 1
  build_wt<<<(128 * 512 + 255) / 256, 256, 0, stream>>>(wl1, wt1a, 512);
  build_wt<<<(128 * 512 + 255) / 256, 256, 0, stream>>>(wr1, wt1b, 512);
  gemm_mfma<512, 8><<<ggrid, 256, 0, stream>>>(x, NN, wt1a, bl1, wt1b, br1, xlr);
  gat_gather<false><<<(NN + 3) / 4, 256, 0, stream>>>(
      xlr, row_off, csr, we1, att1, bo1, prelu, h1);

  // layer 2
  build_wt<<<(128 * 64 + 255) / 256, 256, 0, stream>>>(wl2, wt2a, 64);
  build_wt<<<(128 * 64 + 255) / 256, 256, 0, stream>>>(wr2, wt2b, 64);
  gemm_mfma<64, 1><<<ggrid, 256, 0, stream>>>(h1, NN, wt2a, bl2, wt2b, br2, xlr);
  gat_gather<true><<<(NN + 3) / 4, 256, 0, stream>>>(
      xlr, row_off, csr, we2, att2, bo2, prelu, out);
}

// Round 14
// 289.713 us; speedup vs baseline: 1.1475x; 1.1475x over previous
//
#include <hip/hip_runtime.h>
#include <hip/hip_bf16.h>
#include <math.h>

#define NN 50000
#define EE 800000
#define NB ((NN + 255) / 256)   // 196 scan blocks

typedef __attribute__((ext_vector_type(8))) short bf16x8;
typedef __attribute__((ext_vector_type(4))) float f32x4;

__device__ __forceinline__ short f2bf(float f) {
  __hip_bfloat16 h = __float2bfloat16(f);   // RTNE
  return __builtin_bit_cast(short, h);
}
__device__ __forceinline__ float bf2f(short h) {
  return __uint_as_float(((unsigned)(unsigned short)h) << 16);
}

typedef const __attribute__((address_space(1))) unsigned int* gas_ptr;
typedef __attribute__((address_space(3))) unsigned int* las_ptr;
__device__ __forceinline__ void gload16(const void* g, void* l) {
  __builtin_amdgcn_global_load_lds((gas_ptr)g, (las_ptr)l, 16, 0, 0);
}

// ---------------------------------------------------------------------------
// Wt builder: w [K][128] f32 -> wt [128][2K] bf16 rows = [hi | lo]
// ---------------------------------------------------------------------------
__global__ void build_wt(const float* __restrict__ w, short* __restrict__ wt, int K)
{
  int idx = blockIdx.x * 256 + threadIdx.x;
  if (idx >= 128 * K) return;
  int k = idx % K;
  int c = idx / K;
  float v = w[(size_t)k * 128 + c];
  short hi = f2bf(v);
  short lo = f2bf(v - bf2f(hi));
  size_t base = (size_t)c * 2 * K;
  wt[base + k] = hi;
  wt[base + K + k] = lo;
}

// ---------------------------------------------------------------------------
// Split-precision MFMA GEMM (round-12, known-good): async global_load_lds
// staging (A f32 in LDS, hi/lo conversion in MFMA phase), linear LDS dest +
// inverse-swizzled global source. bn=0 = 3-product; bn=1 = 1-product bf16.
// ---------------------------------------------------------------------------
template <int K, int KS>   // KS = K/64
__global__ __launch_bounds__(256) void gemm_mfma(
    const float* __restrict__ A, int M,
    const short* __restrict__ Wt0, const float* __restrict__ b0,
    const short* __restrict__ Wt1, const float* __restrict__ b1,
    float* __restrict__ out)
{
  const int bn = blockIdx.y;
  const bool full = (bn == 0);
  const short* __restrict__ Wt = bn ? Wt1 : Wt0;
  const float* __restrict__ bias = bn ? b1 : b0;
  __shared__ __align__(16) float As_f32[128][64];   // 32 KB
  __shared__ __align__(16) short Ws_hi[128][64];    // 16 KB
  __shared__ __align__(16) short Ws_lo[128][64];    // 16 KB
  const int tid = threadIdx.x;
  const int m0 = blockIdx.x * 128;
  const int lane = tid & 63;
  const int wv = tid >> 6;
  const int wr = wv >> 1, wc = wv & 1;
  const int rsel = lane & 15, ksel = lane >> 4, sx = lane & 7;

  f32x4 acc[4][4];
#pragma unroll
  for (int i = 0; i < 4; ++i)
#pragma unroll
    for (int j = 0; j < 4; ++j) acc[i][j] = (f32x4)(0.f);

  for (int t = 0; t < KS; ++t) {
    const int k0 = t * 64;
#pragma unroll
    for (int i = 0; i < 8; ++i) {
      int L = i * 256 + tid;
      int m = L >> 4, s = L & 15;
      int row = m0 + m;
      row = row < M ? row : M - 1;
      const float* g = A + (size_t)row * K + k0 + ((s ^ ((m & 7) << 1)) << 2);
      gload16(g, (char*)As_f32 + (size_t)L * 16);
    }
#pragma unroll
    for (int i = 0; i < 4; ++i) {
      int L = i * 256 + tid;
      int c = L >> 3, sl = L & 7;
      const short* g = Wt + (size_t)c * (2 * K) + k0 + ((sl ^ (c & 7)) << 3);
      gload16(g, (char*)Ws_hi + (size_t)L * 16);
    }
    if (full) {
#pragma unroll
      for (int i = 0; i < 4; ++i) {
        int L = i * 256 + tid;
        int c = L >> 3, sl = L & 7;
        const short* g = Wt + (size_t)c * (2 * K) + K + k0 + ((sl ^ (c & 7)) << 3);
        gload16(g, (char*)Ws_lo + (size_t)L * 16);
      }
    }
    __syncthreads();
#pragma unroll
    for (int kk = 0; kk < 2; ++kk) {
      bf16x8 ah[4], al[4], bh[4], bl[4];
#pragma unroll
      for (int mf = 0; mf < 4; ++mf) {
        int r = wr * 64 + mf * 16 + rsel;
        int phys = (kk * 8 + ksel * 2) ^ (sx << 1);
        f32x4 a0 = *reinterpret_cast<const f32x4*>(&As_f32[r][phys * 4]);
        f32x4 a1 = *reinterpret_cast<const f32x4*>(&As_f32[r][phys * 4 + 4]);
        float xs[8] = {a0.x, a0.y, a0.z, a0.w, a1.x, a1.y, a1.z, a1.w};
        bf16x8 hi, lo;
#pragma unroll
        for (int j = 0; j < 8; ++j) {
          short h = f2bf(xs[j]);
          hi[j] = h;
          lo[j] = f2bf(xs[j] - bf2f(h));
        }
        ah[mf] = hi;
        al[mf] = lo;
      }
#pragma unroll
      for (int cf = 0; cf < 4; ++cf) {
        int r = wc * 64 + cf * 16 + rsel;
        int sl = ((kk * 4 + ksel) ^ sx) * 8;
        bh[cf] = *reinterpret_cast<const bf16x8*>(&Ws_hi[r][sl]);
        if (full) bl[cf] = *reinterpret_cast<const bf16x8*>(&Ws_lo[r][sl]);
      }
#pragma unroll
      for (int mf = 0; mf < 4; ++mf)
#pragma unroll
        for (int cf = 0; cf < 4; ++cf)
          acc[mf][cf] = __builtin_amdgcn_mfma_f32_16x16x32_bf16(
              ah[mf], bh[cf], acc[mf][cf], 0, 0, 0);
      if (full) {
#pragma unroll
        for (int mf = 0; mf < 4; ++mf)
#pragma unroll
          for (int cf = 0; cf < 4; ++cf) {
            acc[mf][cf] = __builtin_amdgcn_mfma_f32_16x16x32_bf16(
                al[mf], bh[cf], acc[mf][cf], 0, 0, 0);
            acc[mf][cf] = __builtin_amdgcn_mfma_f32_16x16x32_bf16(
                ah[mf], bl[cf], acc[mf][cf], 0, 0, 0);
          }
      }
    }
    __syncthreads();
  }
#pragma unroll
  for (int mf = 0; mf < 4; ++mf) {
#pragma unroll
    for (int j = 0; j < 4; ++j) {
      int row = m0 + wr * 64 + mf * 16 + ksel * 4 + j;
      if (row >= M) continue;
#pragma unroll
      for (int cf = 0; cf < 4; ++cf) {
        int col = wc * 64 + cf * 16 + rsel;
        out[(size_t)row * 256 + bn * 128 + col] = acc[mf][cf][j] + bias[col];
      }
    }
  }
}

// ---------------------------------------------------------------------------
// CSR build: ONE atomic pass (count + position), scan, atomic-free scatter.
// ---------------------------------------------------------------------------
__global__ void count_pos(const int* __restrict__ ei, int* __restrict__ deg,
                          int* __restrict__ pos)
{
  int e = blockIdx.x * 256 + threadIdx.x;
  if (e >= EE) return;
  pos[e] = atomicAdd(&deg[ei[EE + e]], 1);
}

__global__ __launch_bounds__(256) void scan_blocks(const int* __restrict__ deg,
                                                   int* __restrict__ row_off,
                                                   int* __restrict__ bsum)
{
  int b = blockIdx.x, tid = threadIdx.x;
  int i = b * 256 + tid;
  int v = (i < NN) ? deg[i] : 0;
  int lane = tid & 63, wv = tid >> 6;
  int x = v;
#pragma unroll
  for (int off = 1; off < 64; off <<= 1) {
    int t = __shfl_up(x, off);
    if (lane >= off) x += t;
  }
  __shared__ int ws[4], wo[4];
  if (lane == 63) ws[wv] = x;
  __syncthreads();
  if (tid == 0) {
    int s = 0;
#pragma unroll
    for (int k = 0; k < 4; ++k) { wo[k] = s; s += ws[k]; }
    bsum[b] = s;
  }
  __syncthreads();
  x += wo[wv];
  if (i < NN) row_off[i + 1] = x;
}

__global__ __launch_bounds__(256) void scan_tops(const int* __restrict__ bsum,
                                                 int* __restrict__ boff)
{
  int tid = threadIdx.x;
  int v = (tid < NB) ? bsum[tid] : 0;
  int lane = tid & 63, wv = tid >> 6;
  int x = v;
#pragma unroll
  for (int off = 1; off < 64; off <<= 1) {
    int t = __shfl_up(x, off);
    if (lane >= off) x += t;
  }
  __shared__ int ws[4], wo[4];
  if (lane == 63) ws[wv] = x;
  __syncthreads();
  if (tid == 0) {
    int s = 0;
#pragma unroll
    for (int k = 0; k < 4; ++k) { wo[k] = s; s += ws[k]; }
  }
  __syncthreads();
  x += wo[wv];
  if (tid < NB) boff[tid] = x - v;   // exclusive
}

__global__ void scan_add(int* __restrict__ row_off, const int* __restrict__ boff)
{
  int i = blockIdx.x * 256 + threadIdx.x;
  if (i == 0) row_off[0] = 0;
  if (i < NN) row_off[i + 1] += boff[blockIdx.x];
}

__global__ void scatter_edges(const int* __restrict__ ei, const float* __restrict__ ea,
                              const int* __restrict__ row_off,
                              const int* __restrict__ pos, float4* __restrict__ csr)
{
  int e = blockIdx.x * 256 + threadIdx.x;
  if (e >= EE) return;
  int s = ei[e];
  int d = ei[EE + e];
  float e0 = ea[(size_t)e * 3 + 0];
  float e1 = ea[(size_t)e * 3 + 1];
  float e2 = ea[(size_t)e * 3 + 2];
  csr[row_off[d] + pos[e]] = make_float4(__int_as_float(s), e0, e1, e2);
}

// ---------------------------------------------------------------------------
// GATv2 gather v4 (round-12 known-good structure), 128-thread blocks
// (2 nodes/block instead of 4) to cut the block-exit convoy penalty from
// per-node degree variance. Round-13's v5 (f32x8, 4x16-lane groups)
// REGRESSED (VGPR 72, occupancy 29%) — do not repeat.
// ---------------------------------------------------------------------------
__device__ __forceinline__ float edge_score(f32x4 xl, f32x4 xr, float e0, float e1,
                                            float e2, f32x4 w0, f32x4 w1, f32x4 w2,
                                            f32x4 at)
{
  f32x4 z = xl + xr;
  z = __builtin_elementwise_fma((f32x4)(e0), w0, z);
  z = __builtin_elementwise_fma((f32x4)(e1), w1, z);
  z = __builtin_elementwise_fma((f32x4)(e2), w2, z);
  f32x4 t = __builtin_elementwise_max(z, 0.2f * z);
  f32x4 p = t * at;
  return (p.x + p.y) + (p.z + p.w);
}

template <bool FINAL>
__global__ __launch_bounds__(128) void gat_gather(
    const float* __restrict__ xlr, const int* __restrict__ row_off,
    const float4* __restrict__ csr,
    const float* __restrict__ we, const float* __restrict__ att,
    const float* __restrict__ bo, const float* __restrict__ pw,
    float* __restrict__ out)
{
  __shared__ __align__(16) float we_s[384];
  __shared__ __align__(16) float att_s[128];
  __shared__ __align__(16) float bo_s[64], pw_s[64];
  int tid = threadIdx.x;
  for (int i = tid; i < 384; i += 128) we_s[i] = we[i];
  if (tid < 128) att_s[tid] = att[tid];
  if (tid < 64) { bo_s[tid] = bo[tid]; pw_s[tid] = FINAL ? pw[tid] : 0.f; }
  __syncthreads();

  int wv = tid >> 6, lane = tid & 63;
  int n = blockIdx.x * 2 + wv;   // NN % 2 == 0

  const int g   = lane >> 5;                           // edge group
  const int sub = lane & 31;
  const int qb  = (sub >> 4) * 64 + (sub & 15) * 4;    // channel quad base

  f32x4 xr = *reinterpret_cast<const f32x4*>(&xlr[(size_t)n * 256 + 128 + qb]);
  f32x4 w0 = *reinterpret_cast<const f32x4*>(&we_s[qb]);
  f32x4 w1 = *reinterpret_cast<const f32x4*>(&we_s[128 + qb]);
  f32x4 w2 = *reinterpret_cast<const f32x4*>(&we_s[256 + qb]);
  f32x4 at = *reinterpret_cast<const f32x4*>(&att_s[qb]);

  int ro = row_off[n], re = row_off[n + 1];
  int len = re - ro;
  int h0 = (len + 1) >> 1;
  int gs = ro + (g ? h0 : 0);
  int ge = g ? re : ro + h0;

  float m = -INFINITY, s = 0.f;
  f32x4 a = (f32x4)(0.f);
  float se0 = 0.f, se1 = 0.f, se2 = 0.f;

  auto PAIR = [&](float4 cA, float4 cB, f32x4 xlA, f32x4 xlB) {
    float vA = edge_score(xlA, xr, cA.y, cA.z, cA.w, w0, w1, w2, at);
    float vB = edge_score(xlB, xr, cB.y, cB.z, cB.w, w0, w1, w2, at);
#pragma unroll
    for (int off = 8; off; off >>= 1) {
      vA += __shfl_xor(vA, off);
      vB += __shfl_xor(vB, off);
    }
    float nm = fmaxf(m, fmaxf(vA, vB));
    float sc = __expf(m - nm);
    float qA = __expf(vA - nm);
    float qB = __expf(vB - nm);
    s = s * sc + qA + qB;
    a = a * sc + (f32x4)(qA) * xlA + (f32x4)(qB) * xlB;
    m = nm;
    se0 += cA.y + cB.y; se1 += cA.z + cB.z; se2 += cA.w + cB.w;
  };
  auto SINGLE = [&](float4 cA) {
    int sA = __float_as_int(cA.x);
    f32x4 xlA = *reinterpret_cast<const f32x4*>(&xlr[(size_t)sA * 256 + qb]);
    float vA = edge_score(xlA, xr, cA.y, cA.z, cA.w, w0, w1, w2, at);
#pragma unroll
    for (int off = 8; off; off >>= 1) vA += __shfl_xor(vA, off);
    float nm = fmaxf(m, vA);
    float sc = __expf(m - nm);
    float qA = __expf(vA - nm);
    s = s * sc + qA;
    a = a * sc + (f32x4)(qA) * xlA;
    m = nm;
    se0 += cA.y; se1 += cA.z; se2 += cA.w;
  };

  if (gs + 1 < ge) {
    float4 cA = csr[gs], cB = csr[gs + 1];
    f32x4 xlA = *reinterpret_cast<const f32x4*>(
        &xlr[(size_t)__float_as_int(cA.x) * 256 + qb]);
    f32x4 xlB = *reinterpret_cast<const f32x4*>(
        &xlr[(size_t)__float_as_int(cB.x) * 256 + qb]);
    int i = gs;
    for (; i + 3 < ge; i += 2) {
      float4 nA = csr[i + 2], nB = csr[i + 3];
      f32x4 nxA = *reinterpret_cast<const f32x4*>(
          &xlr[(size_t)__float_as_int(nA.x) * 256 + qb]);
      f32x4 nxB = *reinterpret_cast<const f32x4*>(
          &xlr[(size_t)__float_as_int(nB.x) * 256 + qb]);
      PAIR(cA, cB, xlA, xlB);
      cA = nA; cB = nB; xlA = nxA; xlB = nxB;
    }
    PAIR(cA, cB, xlA, xlB);
    i += 2;
    if (i < ge) SINGLE(csr[i]);
  } else if (gs < ge) {
    SINGLE(csr[gs]);
  }

  // ---- merge the two edge-groups ----
  {
    float m2 = __shfl_xor(m, 32);
    float s2 = __shfl_xor(s, 32);
    f32x4 a2;
    a2.x = __shfl_xor(a.x, 32);
    a2.y = __shfl_xor(a.y, 32);
    a2.z = __shfl_xor(a.z, 32);
    a2.w = __shfl_xor(a.w, 32);
    float nm = fmaxf(m, m2);
    nm = (nm == -INFINITY) ? 0.f : nm;   // both-empty guard (no NaN)
    float c1 = __expf(m - nm);
    float c2 = __expf(m2 - nm);
    s = s * c1 + s2 * c2;
    a = a * (f32x4)(c1) + a2 * (f32x4)(c2);
    m = nm;
    se0 += __shfl_xor(se0, 32);
    se1 += __shfl_xor(se1, 32);
    se2 += __shfl_xor(se2, 32);
  }

  // ---- self-loop: src = n, attr = mean of in-edge attrs ----
  {
    float inv = 1.f / fmaxf((float)len, 1.f);
    float me0 = se0 * inv, me1 = se1 * inv, me2 = se2 * inv;
    f32x4 xlS = *reinterpret_cast<const f32x4*>(&xlr[(size_t)n * 256 + qb]);
    float vS = edge_score(xlS, xr, me0, me1, me2, w0, w1, w2, at);
#pragma unroll
    for (int off = 8; off; off >>= 1) vS += __shfl_xor(vS, off);
    float nm = fmaxf(m, vS);
    float sc = __expf(m - nm);
    float qS = __expf(vS - nm);
    s = s * sc + qS;
    a = a * sc + (f32x4)(qS) * xlS;
  }

  // ---- head mean + bias (+PReLU), write by lanes 0-15 ----
  f32x4 f = a * (f32x4)(1.f / s);
  f32x4 gxt;
  gxt.x = __shfl_xor(f.x, 16);
  gxt.y = __shfl_xor(f.y, 16);
  gxt.z = __shfl_xor(f.z, 16);
  gxt.w = __shfl_xor(f.w, 16);
  if (lane < 16) {
    int col = (sub & 15) * 4;
    f32x4 b4 = *reinterpret_cast<const f32x4*>(&bo_s[col]);
    f32x4 r = 0.5f * (f + gxt) + b4;
    if (FINAL) {
      f32x4 p4 = *reinterpret_cast<const f32x4*>(&pw_s[col]);
      r.x = (r.x >= 0.f) ? r.x : p4.x * r.x;
      r.y = (r.y >= 0.f) ? r.y : p4.y * r.y;
      r.z = (r.z >= 0.f) ? r.z : p4.z * r.z;
      r.w = (r.w >= 0.f) ? r.w : p4.w * r.w;
    }
    *reinterpret_cast<f32x4*>(&out[(size_t)n * 64 + col]) = r;
  }
}

// ---------------------------------------------------------------------------
extern "C" void kernel_launch(void* const* d_in, const int* in_sizes, int n_in,
                              void* d_out, int out_size, void* d_ws, size_t ws_size,
                              hipStream_t stream)
{
  const float* x     = (const float*)d_in[0];
  const int*   ei    = (const int*)d_in[1];
  const float* eattr = (const float*)d_in[2];
  const float* wl1 = (const float*)d_in[3];
  const float* bl1 = (const float*)d_in[4];
  const float* wr1 = (const float*)d_in[5];
  const float* br1 = (const float*)d_in[6];
  const float* we1 = (const float*)d_in[7];
  const float* att1 = (const float*)d_in[8];
  const float* bo1 = (const float*)d_in[9];
  const float* wl2 = (const float*)d_in[10];
  const float* bl2 = (const float*)d_in[11];
  const float* wr2 = (const float*)d_in[12];
  const float* br2 = (const float*)d_in[13];
  const float* we2 = (const float*)d_in[14];
  const float* att2 = (const float*)d_in[15];
  const float* bo2 = (const float*)d_in[16];
  const float* prelu = (const float*)d_in[17];
  float* out = (float*)d_out;

  float* fws  = (float*)d_ws;
  float* xlr  = fws;                             // N*256 f32
  float* h1   = xlr + (size_t)NN * 256;          // N*64 f32
  float4* csr = (float4*)(h1 + (size_t)NN * 64); // EE float4
  int* deg     = (int*)(csr + EE);               // N
  int* row_off = deg + NN;                       // N+1
  int* bsum    = row_off + NN + 1;               // NB
  int* boff    = bsum + NB;                      // NB
  int* pos     = boff + NB;                      // EE

  // wt1 aliases h1 (dead until gat1 writes h1); wt2 aliases deg (dead after
  // scan; build_wt2 launches after scatter_edges).
  short* wt1a = (short*)h1;
  short* wt1b = wt1a + (size_t)128 * 1024;
  short* wt2a = (short*)deg;
  short* wt2b = wt2a + (size_t)128 * 128;

  hipMemsetAsync(deg, 0, (size_t)NN * 4, stream);

  int ebl = (EE + 255) / 256;

  count_pos<<<ebl, 256, 0, stream>>>(ei, deg, pos);
  scan_blocks<<<NB, 256, 0, stream>>>(deg, row_off, bsum);
  scan_tops<<<1, 256, 0, stream>>>(bsum, boff);
  scan_add<<<NB, 256, 0, stream>>>(row_off, boff);
  scatter_edges<<<ebl, 256, 0, stream>>>(ei, eattr, row_off, pos, csr);

  dim3 ggrid((NN + 127) / 128, 2);

  // layer 1
  build_wt<<<(128 * 512 + 255) / 256, 256, 0, stream>>>(wl1, wt1a, 512);
  build_wt<<<(128 * 512 + 255) / 256, 256, 0, stream>>>(wr1, wt1b, 512);
  gemm_mfma<512, 8><<<ggrid, 256, 0, stream>>>(x, NN, wt1a, bl1, wt1b, br1, xlr);
  gat_gather<false><<<NN / 2, 128, 0, stream>>>(
      xlr, row_off, csr, we1, att1, bo1, prelu, h1);

  // layer 2
  build_wt<<<(128 * 64 + 255) / 256, 256, 0, stream>>>(wl2, wt2a, 64);
  build_wt<<<(128 * 64 + 255) / 256, 256, 0, stream>>>(wr2, wt2b, 64);
  gemm_mfma<64, 1><<<ggrid, 256, 0, stream>>>(h1, NN, wt2a, bl2, wt2b, br2, xlr);
  gat_gather<true><<<NN / 2, 128, 0, stream>>>(
      xlr, row_off, csr, we2, att2, bo2, prelu, out);
}

// Round 15
// 277.438 us; speedup vs baseline: 1.1983x; 1.0442x over previous
//
#include <hip/hip_runtime.h>
#include <hip/hip_bf16.h>
#include <math.h>

#define NN 50000
#define EE 800000
#define NB ((NN + 255) / 256)   // 196 scan blocks

typedef __attribute__((ext_vector_type(8))) short bf16x8;
typedef __attribute__((ext_vector_type(4))) float f32x4;

__device__ __forceinline__ short f2bf(float f) {
  __hip_bfloat16 h = __float2bfloat16(f);   // RTNE
  return __builtin_bit_cast(short, h);
}
__device__ __forceinline__ float bf2f(short h) {
  return __uint_as_float(((unsigned)(unsigned short)h) << 16);
}

typedef const __attribute__((address_space(1))) unsigned int* gas_ptr;
typedef __attribute__((address_space(3))) unsigned int* las_ptr;
__device__ __forceinline__ void gload16(const void* g, void* l) {
  __builtin_amdgcn_global_load_lds((gas_ptr)g, (las_ptr)l, 16, 0, 0);
}

// 16-lane sum reduce, VALU-only (DPP), no DS ops. Four involution pairings:
// row_mirror(0x140), row_half_mirror(0x141), quad_perm(3,2,1,0)=0x1B,
// quad_perm(1,0,3,2)=0xB1 — after 4 adds every lane in the 16-row has the sum.
__device__ __forceinline__ float dpp_red16(float v) {
  v += __int_as_float(__builtin_amdgcn_update_dpp(0, __float_as_int(v), 0x140, 0xF, 0xF, true));
  v += __int_as_float(__builtin_amdgcn_update_dpp(0, __float_as_int(v), 0x141, 0xF, 0xF, true));
  v += __int_as_float(__builtin_amdgcn_update_dpp(0, __float_as_int(v), 0x01B, 0xF, 0xF, true));
  v += __int_as_float(__builtin_amdgcn_update_dpp(0, __float_as_int(v), 0x0B1, 0xF, 0xF, true));
  return v;
}

// ---------------------------------------------------------------------------
// Wt builder: w [K][128] f32 -> wt [128][2K] bf16 rows = [hi | lo]
// ---------------------------------------------------------------------------
__global__ void build_wt(const float* __restrict__ w, short* __restrict__ wt, int K)
{
  int idx = blockIdx.x * 256 + threadIdx.x;
  if (idx >= 128 * K) return;
  int k = idx % K;
  int c = idx / K;
  float v = w[(size_t)k * 128 + c];
  short hi = f2bf(v);
  short lo = f2bf(v - bf2f(hi));
  size_t base = (size_t)c * 2 * K;
  wt[base + k] = hi;
  wt[base + K + k] = lo;
}

// ---------------------------------------------------------------------------
// Split-precision MFMA GEMM, round-15: BK=32, LDS 32KB (As_f32 16K + Ws 8K+8K)
// -> 4 blocks/CU (16 waves/CU, 2x round-12 TLP). Async global_load_lds
// staging, hi/lo conversion in MFMA phase, linear LDS dest + inverse-swizzled
// global source (A: 3-bit slot XOR per row, W: 2-bit). bn=0 = 3-product
// f32-accurate; bn=1 = 1-product bf16 (scores-only path).
// History: r7 direct-W and r9 reg-prefetch REGRESSED; r11 showed stage chain
// bound; r12 gload_lds fixed it; r15 doubles TLP via smaller LDS.
// ---------------------------------------------------------------------------
template <int K, int KS>   // KS = K/32
__global__ __launch_bounds__(256) void gemm_mfma(
    const float* __restrict__ A, int M,
    const short* __restrict__ Wt0, const float* __restrict__ b0,
    const short* __restrict__ Wt1, const float* __restrict__ b1,
    float* __restrict__ out)
{
  const int bn = blockIdx.y;
  const bool full = (bn == 0);
  const short* __restrict__ Wt = bn ? Wt1 : Wt0;
  const float* __restrict__ bias = bn ? b1 : b0;
  __shared__ __align__(16) float As_f32[128][32];   // 16 KB
  __shared__ __align__(16) short Ws_hi[128][32];    //  8 KB
  __shared__ __align__(16) short Ws_lo[128][32];    //  8 KB
  const int tid = threadIdx.x;
  const int m0 = blockIdx.x * 128;
  const int lane = tid & 63;
  const int wv = tid >> 6;
  const int wr = wv >> 1, wc = wv & 1;
  const int rsel = lane & 15, ksel = lane >> 4;
  const int r8 = lane & 7, r4 = lane & 3;   // == row&7 / row&3 (rows = ..+rsel)

  f32x4 acc[4][4];
#pragma unroll
  for (int i = 0; i < 4; ++i)
#pragma unroll
    for (int j = 0; j < 4; ++j) acc[i][j] = (f32x4)(0.f);

  for (int t = 0; t < KS; ++t) {
    const int k0 = t * 32;
    // ---- async stage A: 128 rows x 32 f32 = 1024 16B-slots, 4/thread ----
#pragma unroll
    for (int i = 0; i < 4; ++i) {
      int L = i * 256 + tid;
      int m = L >> 3, s = L & 7;
      int row = m0 + m;
      row = row < M ? row : M - 1;
      const float* g = A + (size_t)row * K + k0 + ((s ^ (m & 7)) << 2);
      gload16(g, (char*)As_f32 + (size_t)L * 16);
    }
    // ---- async stage W hi (+lo if full): 512 slots each, 2/thread ----
#pragma unroll
    for (int i = 0; i < 2; ++i) {
      int L = i * 256 + tid;
      int c = L >> 2, sl = L & 3;
      const short* g = Wt + (size_t)c * (2 * K) + k0 + ((sl ^ (c & 3)) << 3);
      gload16(g, (char*)Ws_hi + (size_t)L * 16);
    }
    if (full) {
#pragma unroll
      for (int i = 0; i < 2; ++i) {
        int L = i * 256 + tid;
        int c = L >> 2, sl = L & 3;
        const short* g = Wt + (size_t)c * (2 * K) + K + k0 + ((sl ^ (c & 3)) << 3);
        gload16(g, (char*)Ws_lo + (size_t)L * 16);
      }
    }
    __syncthreads();
    // ---- MFMA: read f32 A, convert hi/lo in-reg, 1 K-step per chunk ----
    {
      bf16x8 ah[4], al[4], bh[4], bl[4];
#pragma unroll
      for (int mf = 0; mf < 4; ++mf) {
        int r = wr * 64 + mf * 16 + rsel;
        int p0 = ((ksel << 1) ^ r8) << 2;         // logical slot 2*ksel
        int p1 = (((ksel << 1) | 1) ^ r8) << 2;   // logical slot 2*ksel+1
        f32x4 a0 = *reinterpret_cast<const f32x4*>(&As_f32[r][p0]);
        f32x4 a1 = *reinterpret_cast<const f32x4*>(&As_f32[r][p1]);
        float xs[8] = {a0.x, a0.y, a0.z, a0.w, a1.x, a1.y, a1.z, a1.w};
        bf16x8 hi, lo;
#pragma unroll
        for (int j = 0; j < 8; ++j) {
          short h = f2bf(xs[j]);
          hi[j] = h;
          lo[j] = f2bf(xs[j] - bf2f(h));
        }
        ah[mf] = hi;
        al[mf] = lo;
      }
#pragma unroll
      for (int cf = 0; cf < 4; ++cf) {
        int r = wc * 64 + cf * 16 + rsel;
        int sl = (ksel ^ r4) << 3;
        bh[cf] = *reinterpret_cast<const bf16x8*>(&Ws_hi[r][sl]);
        if (full) bl[cf] = *reinterpret_cast<const bf16x8*>(&Ws_lo[r][sl]);
      }
#pragma unroll
      for (int mf = 0; mf < 4; ++mf)
#pragma unroll
        for (int cf = 0; cf < 4; ++cf)
          acc[mf][cf] = __builtin_amdgcn_mfma_f32_16x16x32_bf16(
              ah[mf], bh[cf], acc[mf][cf], 0, 0, 0);
      if (full) {
#pragma unroll
        for (int mf = 0; mf < 4; ++mf)
#pragma unroll
          for (int cf = 0; cf < 4; ++cf) {
            acc[mf][cf] = __builtin_amdgcn_mfma_f32_16x16x32_bf16(
                al[mf], bh[cf], acc[mf][cf], 0, 0, 0);
            acc[mf][cf] = __builtin_amdgcn_mfma_f32_16x16x32_bf16(
                ah[mf], bl[cf], acc[mf][cf], 0, 0, 0);
          }
      }
    }
    __syncthreads();
  }
  // ---- epilogue ----
#pragma unroll
  for (int mf = 0; mf < 4; ++mf) {
#pragma unroll
    for (int j = 0; j < 4; ++j) {
      int row = m0 + wr * 64 + mf * 16 + ksel * 4 + j;
      if (row >= M) continue;
#pragma unroll
      for (int cf = 0; cf < 4; ++cf) {
        int col = wc * 64 + cf * 16 + rsel;
        out[(size_t)row * 256 + bn * 128 + col] = acc[mf][cf][j] + bias[col];
      }
    }
  }
}

// ---------------------------------------------------------------------------
// CSR build: ONE atomic pass (count + position), scan, atomic-free scatter.
// ---------------------------------------------------------------------------
__global__ void count_pos(const int* __restrict__ ei, int* __restrict__ deg,
                          int* __restrict__ pos)
{
  int e = blockIdx.x * 256 + threadIdx.x;
  if (e >= EE) return;
  pos[e] = atomicAdd(&deg[ei[EE + e]], 1);
}

__global__ __launch_bounds__(256) void scan_blocks(const int* __restrict__ deg,
                                                   int* __restrict__ row_off,
                                                   int* __restrict__ bsum)
{
  int b = blockIdx.x, tid = threadIdx.x;
  int i = b * 256 + tid;
  int v = (i < NN) ? deg[i] : 0;
  int lane = tid & 63, wv = tid >> 6;
  int x = v;
#pragma unroll
  for (int off = 1; off < 64; off <<= 1) {
    int t = __shfl_up(x, off);
    if (lane >= off) x += t;
  }
  __shared__ int ws[4], wo[4];
  if (lane == 63) ws[wv] = x;
  __syncthreads();
  if (tid == 0) {
    int s = 0;
#pragma unroll
    for (int k = 0; k < 4; ++k) { wo[k] = s; s += ws[k]; }
    bsum[b] = s;
  }
  __syncthreads();
  x += wo[wv];
  if (i < NN) row_off[i + 1] = x;
}

__global__ __launch_bounds__(256) void scan_tops(const int* __restrict__ bsum,
                                                 int* __restrict__ boff)
{
  int tid = threadIdx.x;
  int v = (tid < NB) ? bsum[tid] : 0;
  int lane = tid & 63, wv = tid >> 6;
  int x = v;
#pragma unroll
  for (int off = 1; off < 64; off <<= 1) {
    int t = __shfl_up(x, off);
    if (lane >= off) x += t;
  }
  __shared__ int ws[4], wo[4];
  if (lane == 63) ws[wv] = x;
  __syncthreads();
  if (tid == 0) {
    int s = 0;
#pragma unroll
    for (int k = 0; k < 4; ++k) { wo[k] = s; s += ws[k]; }
  }
  __syncthreads();
  x += wo[wv];
  if (tid < NB) boff[tid] = x - v;   // exclusive
}

__global__ void scan_add(int* __restrict__ row_off, const int* __restrict__ boff)
{
  int i = blockIdx.x * 256 + threadIdx.x;
  if (i == 0) row_off[0] = 0;
  if (i < NN) row_off[i + 1] += boff[blockIdx.x];
}

__global__ void scatter_edges(const int* __restrict__ ei, const float* __restrict__ ea,
                              const int* __restrict__ row_off,
                              const int* __restrict__ pos, float4* __restrict__ csr)
{
  int e = blockIdx.x * 256 + threadIdx.x;
  if (e >= EE) return;
  int s = ei[e];
  int d = ei[EE + e];
  float e0 = ea[(size_t)e * 3 + 0];
  float e1 = ea[(size_t)e * 3 + 1];
  float e2 = ea[(size_t)e * 3 + 2];
  csr[row_off[d] + pos[e]] = make_float4(__int_as_float(s), e0, e1, e2);
}

// ---------------------------------------------------------------------------
// GATv2 gather v4.2: round-14 structure (128-thread blocks, 2 nodes/block,
// two 32-lane edge-groups, float4 quads, 1-pair pipeline), with the inner
// score reduce switched from __shfl_xor (DS pipe) to VALU-only DPP adds.
// Round-13's v5 (f32x8, 4x16 groups) REGRESSED via occupancy — do not repeat.
// ---------------------------------------------------------------------------
__device__ __forceinline__ float edge_score(f32x4 xl, f32x4 xr, float e0, float e1,
                                            float e2, f32x4 w0, f32x4 w1, f32x4 w2,
                                            f32x4 at)
{
  f32x4 z = xl + xr;
  z = __builtin_elementwise_fma((f32x4)(e0), w0, z);
  z = __builtin_elementwise_fma((f32x4)(e1), w1, z);
  z = __builtin_elementwise_fma((f32x4)(e2), w2, z);
  f32x4 t = __builtin_elementwise_max(z, 0.2f * z);
  f32x4 p = t * at;
  return (p.x + p.y) + (p.z + p.w);
}

template <bool FINAL>
__global__ __launch_bounds__(128) void gat_gather(
    const float* __restrict__ xlr, const int* __restrict__ row_off,
    const float4* __restrict__ csr,
    const float* __restrict__ we, const float* __restrict__ att,
    const float* __restrict__ bo, const float* __restrict__ pw,
    float* __restrict__ out)
{
  __shared__ __align__(16) float we_s[384];
  __shared__ __align__(16) float att_s[128];
  __shared__ __align__(16) float bo_s[64], pw_s[64];
  int tid = threadIdx.x;
  for (int i = tid; i < 384; i += 128) we_s[i] = we[i];
  if (tid < 128) att_s[tid] = att[tid];
  if (tid < 64) { bo_s[tid] = bo[tid]; pw_s[tid] = FINAL ? pw[tid] : 0.f; }
  __syncthreads();

  int wv = tid >> 6, lane = tid & 63;
  int n = blockIdx.x * 2 + wv;   // NN % 2 == 0

  const int g   = lane >> 5;                           // edge group
  const int sub = lane & 31;
  const int qb  = (sub >> 4) * 64 + (sub & 15) * 4;    // channel quad base

  f32x4 xr = *reinterpret_cast<const f32x4*>(&xlr[(size_t)n * 256 + 128 + qb]);
  f32x4 w0 = *reinterpret_cast<const f32x4*>(&we_s[qb]);
  f32x4 w1 = *reinterpret_cast<const f32x4*>(&we_s[128 + qb]);
  f32x4 w2 = *reinterpret_cast<const f32x4*>(&we_s[256 + qb]);
  f32x4 at = *reinterpret_cast<const f32x4*>(&att_s[qb]);

  int ro = row_off[n], re = row_off[n + 1];
  int len = re - ro;
  int h0 = (len + 1) >> 1;
  int gs = ro + (g ? h0 : 0);
  int ge = g ? re : ro + h0;

  float m = -INFINITY, s = 0.f;
  f32x4 a = (f32x4)(0.f);
  float se0 = 0.f, se1 = 0.f, se2 = 0.f;

  auto PAIR = [&](float4 cA, float4 cB, f32x4 xlA, f32x4 xlB) {
    float vA = edge_score(xlA, xr, cA.y, cA.z, cA.w, w0, w1, w2, at);
    float vB = edge_score(xlB, xr, cB.y, cB.z, cB.w, w0, w1, w2, at);
    vA = dpp_red16(vA);
    vB = dpp_red16(vB);
    float nm = fmaxf(m, fmaxf(vA, vB));
    float sc = __expf(m - nm);
    float qA = __expf(vA - nm);
    float qB = __expf(vB - nm);
    s = s * sc + qA + qB;
    a = a * sc + (f32x4)(qA) * xlA + (f32x4)(qB) * xlB;
    m = nm;
    se0 += cA.y + cB.y; se1 += cA.z + cB.z; se2 += cA.w + cB.w;
  };
  auto SINGLE = [&](float4 cA) {
    int sA = __float_as_int(cA.x);
    f32x4 xlA = *reinterpret_cast<const f32x4*>(&xlr[(size_t)sA * 256 + qb]);
    float vA = edge_score(xlA, xr, cA.y, cA.z, cA.w, w0, w1, w2, at);
    vA = dpp_red16(vA);
    float nm = fmaxf(m, vA);
    float sc = __expf(m - nm);
    float qA = __expf(vA - nm);
    s = s * sc + qA;
    a = a * sc + (f32x4)(qA) * xlA;
    m = nm;
    se0 += cA.y; se1 += cA.z; se2 += cA.w;
  };

  if (gs + 1 < ge) {
    float4 cA = csr[gs], cB = csr[gs + 1];
    f32x4 xlA = *reinterpret_cast<const f32x4*>(
        &xlr[(size_t)__float_as_int(cA.x) * 256 + qb]);
    f32x4 xlB = *reinterpret_cast<const f32x4*>(
        &xlr[(size_t)__float_as_int(cB.x) * 256 + qb]);
    int i = gs;
    for (; i + 3 < ge; i += 2) {
      float4 nA = csr[i + 2], nB = csr[i + 3];
      f32x4 nxA = *reinterpret_cast<const f32x4*>(
          &xlr[(size_t)__float_as_int(nA.x) * 256 + qb]);
      f32x4 nxB = *reinterpret_cast<const f32x4*>(
          &xlr[(size_t)__float_as_int(nB.x) * 256 + qb]);
      PAIR(cA, cB, xlA, xlB);
      cA = nA; cB = nB; xlA = nxA; xlB = nxB;
    }
    PAIR(cA, cB, xlA, xlB);
    i += 2;
    if (i < ge) SINGLE(csr[i]);
  } else if (gs < ge) {
    SINGLE(csr[gs]);
  }

  // ---- merge the two edge-groups (once per node; shfl fine here) ----
  {
    float m2 = __shfl_xor(m, 32);
    float s2 = __shfl_xor(s, 32);
    f32x4 a2;
    a2.x = __shfl_xor(a.x, 32);
    a2.y = __shfl_xor(a.y, 32);
    a2.z = __shfl_xor(a.z, 32);
    a2.w = __shfl_xor(a.w, 32);
    float nm = fmaxf(m, m2);
    nm = (nm == -INFINITY) ? 0.f : nm;   // both-empty guard (no NaN)
    float c1 = __expf(m - nm);
    float c2 = __expf(m2 - nm);
    s = s * c1 + s2 * c2;
    a = a * (f32x4)(c1) + a2 * (f32x4)(c2);
    m = nm;
    se0 += __shfl_xor(se0, 32);
    se1 += __shfl_xor(se1, 32);
    se2 += __shfl_xor(se2, 32);
  }

  // ---- self-loop: src = n, attr = mean of in-edge attrs ----
  {
    float inv = 1.f / fmaxf((float)len, 1.f);
    float me0 = se0 * inv, me1 = se1 * inv, me2 = se2 * inv;
    f32x4 xlS = *reinterpret_cast<const f32x4*>(&xlr[(size_t)n * 256 + qb]);
    float vS = edge_score(xlS, xr, me0, me1, me2, w0, w1, w2, at);
    vS = dpp_red16(vS);
    float nm = fmaxf(m, vS);
    float sc = __expf(m - nm);
    float qS = __expf(vS - nm);
    s = s * sc + qS;
    a = a * sc + (f32x4)(qS) * xlS;
  }

  // ---- head mean + bias (+PReLU), write by lanes 0-15 ----
  f32x4 f = a * (f32x4)(1.f / s);
  f32x4 gxt;
  gxt.x = __shfl_xor(f.x, 16);
  gxt.y = __shfl_xor(f.y, 16);
  gxt.z = __shfl_xor(f.z, 16);
  gxt.w = __shfl_xor(f.w, 16);
  if (lane < 16) {
    int col = (sub & 15) * 4;
    f32x4 b4 = *reinterpret_cast<const f32x4*>(&bo_s[col]);
    f32x4 r = 0.5f * (f + gxt) + b4;
    if (FINAL) {
      f32x4 p4 = *reinterpret_cast<const f32x4*>(&pw_s[col]);
      r.x = (r.x >= 0.f) ? r.x : p4.x * r.x;
      r.y = (r.y >= 0.f) ? r.y : p4.y * r.y;
      r.z = (r.z >= 0.f) ? r.z : p4.z * r.z;
      r.w = (r.w >= 0.f) ? r.w : p4.w * r.w;
    }
    *reinterpret_cast<f32x4*>(&out[(size_t)n * 64 + col]) = r;
  }
}

// ---------------------------------------------------------------------------
extern "C" void kernel_launch(void* const* d_in, const int* in_sizes, int n_in,
                              void* d_out, int out_size, void* d_ws, size_t ws_size,
                              hipStream_t stream)
{
  const float* x     = (const float*)d_in[0];
  const int*   ei    = (const int*)d_in[1];
  const float* eattr = (const float*)d_in[2];
  const float* wl1 = (const float*)d_in[3];
  const float* bl1 = (const float*)d_in[4];
  const float* wr1 = (const float*)d_in[5];
  const float* br1 = (const float*)d_in[6];
  const float* we1 = (const float*)d_in[7];
  const float* att1 = (const float*)d_in[8];
  const float* bo1 = (const float*)d_in[9];
  const float* wl2 = (const float*)d_in[10];
  const float* bl2 = (const float*)d_in[11];
  const float* wr2 = (const float*)d_in[12];
  const float* br2 = (const float*)d_in[13];
  const float* we2 = (const float*)d_in[14];
  const float* att2 = (const float*)d_in[15];
  const float* bo2 = (const float*)d_in[16];
  const float* prelu = (const float*)d_in[17];
  float* out = (float*)d_out;

  float* fws  = (float*)d_ws;
  float* xlr  = fws;                             // N*256 f32
  float* h1   = xlr + (size_t)NN * 256;          // N*64 f32
  float4* csr = (float4*)(h1 + (size_t)NN * 64); // EE float4
  int* deg     = (int*)(csr + EE);               // N
  int* row_off = deg + NN;                       // N+1
  int* bsum    = row_off + NN + 1;               // NB
  int* boff    = bsum + NB;                      // NB
  int* pos     = boff + NB;                      // EE

  // wt1 aliases h1 (dead until gat1 writes h1); wt2 aliases deg (dead after
  // scan; build_wt2 launches after scatter_edges).
  short* wt1a = (short*)h1;
  short* wt1b = wt1a + (size_t)128 * 1024;
  short* wt2a = (short*)deg;
  short* wt2b = wt2a + (size_t)128 * 128;

  hipMemsetAsync(deg, 0, (size_t)NN * 4, stream);

  int ebl = (EE + 255) / 256;

  count_pos<<<ebl, 256, 0, stream>>>(ei, deg, pos);
  scan_blocks<<<NB, 256, 0, stream>>>(deg, row_off, bsum);
  scan_tops<<<1, 256, 0, stream>>>(bsum, boff);
  scan_add<<<NB, 256, 0, stream>>>(row_off, boff);
  scatter_edges<<<ebl, 256, 0, stream>>>(ei, eattr, row_off, pos, csr);

  dim3 ggrid((NN + 127) / 128, 2);

  // layer 1
  build_wt<<<(128 * 512 + 255) / 256, 256, 0, stream>>>(wl1, wt1a, 512);
  build_wt<<<(128 * 512 + 255) / 256, 256, 0, stream>>>(wr1, wt1b, 512);
  gemm_mfma<512, 16><<<ggrid, 256, 0, stream>>>(x, NN, wt1a, bl1, wt1b, br1, xlr);
  gat_gather<false><<<NN / 2, 128, 0, stream>>>(
      xlr, row_off, csr, we1, att1, bo1, prelu, h1);

  // layer 2
  build_wt<<<(128 * 64 + 255) / 256, 256, 0, stream>>>(wl2, wt2a, 64);
  build_wt<<<(128 * 64 + 255) / 256, 256, 0, stream>>>(wr2, wt2b, 64);
  gemm_mfma<64, 2><<<ggrid, 256, 0, stream>>>(h1, NN, wt2a, bl2, wt2b, br2, xlr);
  gat_gather<true><<<NN / 2, 128, 0, stream>>>(
      xlr, row_off, csr, we2, att2, bo2, prelu, out);
}